// Round 8
// baseline (688.270 us; speedup 1.0000x reference)
//
#include <hip/hip_runtime.h>
#include <math.h>

// Problem constants
constexpr int B_ = 8, S_ = 32, D_ = 256, M_ = 2048;
constexpr int N_ = S_ * B_;          // 256 (t,b) pairs, n = t*B + b
constexpr int TK = 8;                // TOPK
constexpr int NSLOT = 256;           // max distinct touched rows (8*31=248)
constexpr int TOPC = 256;            // precomputed top-C of L0 per (t,b)
constexpr int NCAND = NSLOT + TOPC;  // 512
constexpr int KSPLIT = 4;            // ctxpart split-K
constexpr int CACHE0 = 192;          // WvWgB rows [CACHE0,256) cached in LDS (64KB)

// ---------------------------------------------------------------------------
// K0: blocks 0..15: WvWgB[i][d] = sum_j Wv[i][j]*Wg[D+j][d]
//     block 16:     bvg[d] = bg[d] + sum_j bv[j]*Wg[D+j][d]
//     blocks 17..80: WkT[j][i] = Wk[i][j]
// ---------------------------------------------------------------------------
__global__ __launch_bounds__(256) void k_wvwgT(const float* __restrict__ Wv,
                                               const float* __restrict__ Wg,
                                               const float* __restrict__ bv,
                                               const float* __restrict__ bg,
                                               const float* __restrict__ Wk,
                                               float* __restrict__ WvWgB,
                                               float* __restrict__ bvg,
                                               float* __restrict__ WkT) {
  int blk = blockIdx.x;
  int tid = threadIdx.x;
  if (blk >= 17) {
    __shared__ float tile[32][33];
    int bb = blk - 17;
    int bx = bb & 7, by = bb >> 3;
    int x0 = bx * 32, y0 = by * 32;
    int tx = tid & 31, ty = tid >> 5;
    for (int j = ty; j < 32; j += 8) tile[j][tx] = Wk[(y0 + j) * D_ + x0 + tx];
    __syncthreads();
    for (int j = ty; j < 32; j += 8) WkT[(x0 + j) * D_ + y0 + tx] = tile[tx][j];
    return;
  }
  if (blk == 16) {
    float a = bg[tid];
#pragma unroll 8
    for (int j = 0; j < D_; ++j) a = fmaf(bv[j], Wg[(size_t)(D_ + j) * D_ + tid], a);
    bvg[tid] = a;
    return;
  }
  int i0 = (blk & 3) * 64, d0 = (blk >> 2) * 64;
  __shared__ float At[64 * 64];  // [j][i]
  __shared__ float Bt[64 * 64];  // [j][d]
  const int r = tid & 63, c = tid >> 6;
  const int lane = tid & 63, wvv = tid >> 6;
  const int tx = lane & 15, ty = lane >> 4;
  const int dg = tx * 4, ig = (wvv * 4 + ty) * 4;
  float acc[4][4];
#pragma unroll
  for (int i = 0; i < 4; ++i)
#pragma unroll
    for (int j = 0; j < 4; ++j) acc[i][j] = 0.f;
  for (int kc = 0; kc < 4; ++kc) {
    __syncthreads();
#pragma unroll
    for (int it = 0; it < 4; ++it) {
      int jq = (c * 4 + it) * 4;
      float4 a = *(const float4*)&Wv[(i0 + r) * D_ + kc * 64 + jq];
      At[(jq + 0) * 64 + r] = a.x; At[(jq + 1) * 64 + r] = a.y;
      At[(jq + 2) * 64 + r] = a.z; At[(jq + 3) * 64 + r] = a.w;
      *(float4*)&Bt[r * 64 + jq] =
          *(const float4*)&Wg[(size_t)(D_ + kc * 64 + r) * D_ + d0 + jq];
    }
    __syncthreads();
#pragma unroll 4
    for (int j = 0; j < 64; ++j) {
      float4 av = *(const float4*)&At[j * 64 + ig];
      float4 bv4 = *(const float4*)&Bt[j * 64 + dg];
      acc[0][0] = fmaf(av.x, bv4.x, acc[0][0]); acc[0][1] = fmaf(av.x, bv4.y, acc[0][1]);
      acc[0][2] = fmaf(av.x, bv4.z, acc[0][2]); acc[0][3] = fmaf(av.x, bv4.w, acc[0][3]);
      acc[1][0] = fmaf(av.y, bv4.x, acc[1][0]); acc[1][1] = fmaf(av.y, bv4.y, acc[1][1]);
      acc[1][2] = fmaf(av.y, bv4.z, acc[1][2]); acc[1][3] = fmaf(av.y, bv4.w, acc[1][3]);
      acc[2][0] = fmaf(av.z, bv4.x, acc[2][0]); acc[2][1] = fmaf(av.z, bv4.y, acc[2][1]);
      acc[2][2] = fmaf(av.z, bv4.z, acc[2][2]); acc[2][3] = fmaf(av.z, bv4.w, acc[2][3]);
      acc[3][0] = fmaf(av.w, bv4.x, acc[3][0]); acc[3][1] = fmaf(av.w, bv4.y, acc[3][1]);
      acc[3][2] = fmaf(av.w, bv4.z, acc[3][2]); acc[3][3] = fmaf(av.w, bv4.w, acc[3][3]);
    }
  }
#pragma unroll
  for (int i = 0; i < 4; ++i)
    *(float4*)&WvWgB[(size_t)(i0 + ig + i) * D_ + d0 + dg] =
        make_float4(acc[i][0], acc[i][1], acc[i][2], acc[i][3]);
}

// ---------------------------------------------------------------------------
// K1: per n=(t,b): q = xt@Wq+bq ; qt[d]=sum_i q[i]*WkT[i][d] ; qbk = q.bk ;
//     xgpre = xt @ Wg[0:D,:]
// ---------------------------------------------------------------------------
__global__ __launch_bounds__(256) void k_qproj(
    const float* __restrict__ x, const float* __restrict__ Wq,
    const float* __restrict__ bq, const float* __restrict__ bk,
    const float* __restrict__ WkT, const float* __restrict__ Wg,
    float* __restrict__ qt, float* __restrict__ qbk, float* __restrict__ xgp) {
  int n = blockIdx.x, tid = threadIdx.x;
  int t = n / B_, b = n % B_;
  __shared__ float xr[D_], qsh[D_];
  __shared__ float red[4];
  xr[tid] = x[(b * S_ + t) * D_ + tid];
  __syncthreads();
  float accq = bq[tid], accg = 0.f;
#pragma unroll 8
  for (int i = 0; i < D_; ++i) {
    float xv = xr[i];
    accq = fmaf(xv, Wq[i * D_ + tid], accq);
    accg = fmaf(xv, Wg[i * D_ + tid], accg);
  }
  qsh[tid] = accq;
  xgp[n * D_ + tid] = accg;
  float p = accq * bk[tid];
  for (int off = 32; off > 0; off >>= 1) p += __shfl_down(p, off, 64);
  if ((tid & 63) == 0) red[tid >> 6] = p;
  __syncthreads();
  float acct = 0.f;
#pragma unroll 8
  for (int i = 0; i < D_; ++i) acct = fmaf(qsh[i], WkT[i * D_ + tid], acct);
  qt[n * D_ + tid] = acct;
  if (tid == 0) qbk[n] = red[0] + red[1] + red[2] + red[3];
}

// ---------------------------------------------------------------------------
// K2: L0[n][m] = (memory[m] . qt[n] + qbk[n]) / 16
// ---------------------------------------------------------------------------
__global__ __launch_bounds__(256) void k_L0(
    const float* __restrict__ qt, const float* __restrict__ mem,
    const float* __restrict__ qbk, float* __restrict__ L0) {
  __shared__ float qtT[64 * 64];
  __shared__ float mT[64 * 64];
  const int tid = threadIdx.x;
  const int m0 = blockIdx.x * 64, n0 = blockIdx.y * 64;
  const int r = tid & 63, c = tid >> 6;
  const int lane = tid & 63, wv = tid >> 6;
  const int tx = lane & 15, ty = lane >> 4;
  const int mg = tx * 4, ng = (wv * 4 + ty) * 4;
  float acc[4][4];
#pragma unroll
  for (int i = 0; i < 4; ++i)
#pragma unroll
    for (int j = 0; j < 4; ++j) acc[i][j] = 0.f;
  for (int kc = 0; kc < 4; ++kc) {
    __syncthreads();
#pragma unroll
    for (int it = 0; it < 4; ++it) {
      int kq = (c * 4 + it) * 4;
      float4 a = *(const float4*)&qt[(n0 + r) * D_ + kc * 64 + kq];
      qtT[(kq + 0) * 64 + r] = a.x; qtT[(kq + 1) * 64 + r] = a.y;
      qtT[(kq + 2) * 64 + r] = a.z; qtT[(kq + 3) * 64 + r] = a.w;
      float4 bm = *(const float4*)&mem[(m0 + r) * D_ + kc * 64 + kq];
      mT[(kq + 0) * 64 + r] = bm.x; mT[(kq + 1) * 64 + r] = bm.y;
      mT[(kq + 2) * 64 + r] = bm.z; mT[(kq + 3) * 64 + r] = bm.w;
    }
    __syncthreads();
#pragma unroll 4
    for (int k = 0; k < 64; ++k) {
      float4 av = *(const float4*)&qtT[k * 64 + ng];
      float4 bv4 = *(const float4*)&mT[k * 64 + mg];
      acc[0][0] = fmaf(av.x, bv4.x, acc[0][0]); acc[0][1] = fmaf(av.x, bv4.y, acc[0][1]);
      acc[0][2] = fmaf(av.x, bv4.z, acc[0][2]); acc[0][3] = fmaf(av.x, bv4.w, acc[0][3]);
      acc[1][0] = fmaf(av.y, bv4.x, acc[1][0]); acc[1][1] = fmaf(av.y, bv4.y, acc[1][1]);
      acc[1][2] = fmaf(av.y, bv4.z, acc[1][2]); acc[1][3] = fmaf(av.y, bv4.w, acc[1][3]);
      acc[2][0] = fmaf(av.z, bv4.x, acc[2][0]); acc[2][1] = fmaf(av.z, bv4.y, acc[2][1]);
      acc[2][2] = fmaf(av.z, bv4.z, acc[2][2]); acc[2][3] = fmaf(av.z, bv4.w, acc[2][3]);
      acc[3][0] = fmaf(av.w, bv4.x, acc[3][0]); acc[3][1] = fmaf(av.w, bv4.y, acc[3][1]);
      acc[3][2] = fmaf(av.w, bv4.z, acc[3][2]); acc[3][3] = fmaf(av.w, bv4.w, acc[3][3]);
    }
  }
#pragma unroll
  for (int i = 0; i < 4; ++i) {
    int n = n0 + ng + i;
    float qbv = qbk[n];
    float4 o;
    o.x = (acc[i][0] + qbv) * 0.0625f; o.y = (acc[i][1] + qbv) * 0.0625f;
    o.z = (acc[i][2] + qbv) * 0.0625f; o.w = (acc[i][3] + qbv) * 0.0625f;
    *(float4*)&L0[n * M_ + m0 + mg] = o;
  }
}

// ---------------------------------------------------------------------------
// K3: fused full bitonic sort (desc, tie idx asc) + top-256 + M0 + SumE0(fp64)
// ---------------------------------------------------------------------------
__global__ __launch_bounds__(1024) void k_sortstats(const float* __restrict__ L0,
                                                    float* __restrict__ topv,
                                                    int* __restrict__ topi,
                                                    float* __restrict__ M0,
                                                    double* __restrict__ SumE0) {
  int n = blockIdx.x, tid = threadIdx.x;
  __shared__ float v[M_];
  __shared__ short ix[M_];
  __shared__ double redd[16];
  for (int m = tid; m < M_; m += 1024) {
    v[m] = L0[(size_t)n * M_ + m];
    ix[m] = (short)m;
  }
  __syncthreads();
  for (int size = 2; size <= M_; size <<= 1) {
    for (int stride = size >> 1; stride > 0; stride >>= 1) {
      const int i = tid;  // exactly M_/2 pairs
      const int pos = 2 * i - (i & (stride - 1));
      const int j = pos + stride;
      const bool desc = ((pos & size) == 0);
      const float va = v[pos], vb2 = v[j];
      const short ia = ix[pos], ib = ix[j];
      const bool aG = (va > vb2) || (va == vb2 && ia < ib);
      if (desc ? !aG : aG) { v[pos] = vb2; v[j] = va; ix[pos] = ib; ix[j] = ia; }
      __syncthreads();
    }
  }
  if (tid < TOPC) {
    topv[n * TOPC + tid] = v[tid];
    topi[n * TOPC + tid] = (int)ix[tid];
  }
  float mx = v[0];
  if (tid == 0) M0[n] = mx;
  double s = 0.0;
  for (int m = tid; m < M_; m += 1024) s += (double)__expf(v[m] - mx);
  for (int off = 32; off > 0; off >>= 1) s += __shfl_down(s, off, 64);
  if ((tid & 63) == 0) redd[tid >> 6] = s;
  __syncthreads();
  if (tid == 0) {
    double t = 0.0;
#pragma unroll
    for (int w = 0; w < 16; ++w) t += redd[w];
    SumE0[n] = t;
  }
}

// ---------------------------------------------------------------------------
// K4: ctxpart[ks][n][d] = sum over ks's K-range of exp(L0-M0)*memory (split-4)
// __expf bit-matches k_scan A1's e0 (same args, same intrinsic).
// ---------------------------------------------------------------------------
__global__ __launch_bounds__(256) void k_ctxpart(
    const float* __restrict__ L0, const float* __restrict__ M0,
    const float* __restrict__ mem, float* __restrict__ ctxp) {
  int ks = blockIdx.x;
  int n0 = blockIdx.y * 32;
  int d0 = blockIdx.z * 64;
  int tid = threadIdx.x;
  __shared__ float Et[64 * 32];
  __shared__ float mTl[64 * 64];
  __shared__ float Msh[32];
  if (tid < 32) Msh[tid] = M0[n0 + tid];
  const int lane = tid & 63, wv = tid >> 6;
  const int tx = lane & 15, ty = lane >> 4;
  const int ng = (wv * 4 + ty) * 2;
  const int dg = tx * 4;
  float acc[2][4] = {{0, 0, 0, 0}, {0, 0, 0, 0}};
  for (int kc = 0; kc < 8; ++kc) {
    int kb = ks * 512 + kc * 64;
    __syncthreads();
#pragma unroll
    for (int j = 0; j < 8; ++j) {
      int ii = tid + 256 * j;
      int nr = ii & 31, kk = ii >> 5;
      Et[kk * 32 + nr] = __expf(L0[(n0 + nr) * M_ + kb + kk] - Msh[nr]);
    }
    {
      int r = tid & 63, c = tid >> 6;
#pragma unroll
      for (int j = 0; j < 4; ++j) {
        int c4 = (c * 4 + j) * 4;
        *(float4*)&mTl[r * 64 + c4] = *(const float4*)&mem[(kb + r) * D_ + d0 + c4];
      }
    }
    __syncthreads();
#pragma unroll 4
    for (int kk = 0; kk < 64; ++kk) {
      float4 mv = *(const float4*)&mTl[kk * 64 + dg];
      float e0v = Et[kk * 32 + ng], e1v = Et[kk * 32 + ng + 1];
      acc[0][0] = fmaf(e0v, mv.x, acc[0][0]); acc[0][1] = fmaf(e0v, mv.y, acc[0][1]);
      acc[0][2] = fmaf(e0v, mv.z, acc[0][2]); acc[0][3] = fmaf(e0v, mv.w, acc[0][3]);
      acc[1][0] = fmaf(e1v, mv.x, acc[1][0]); acc[1][1] = fmaf(e1v, mv.y, acc[1][1]);
      acc[1][2] = fmaf(e1v, mv.z, acc[1][2]); acc[1][3] = fmaf(e1v, mv.w, acc[1][3]);
    }
  }
#pragma unroll
  for (int i = 0; i < 2; ++i) {
    int n = n0 + ng + i;
    *(float4*)&ctxp[((size_t)ks * N_ + n) * D_ + d0 + dg] =
        make_float4(acc[i][0], acc[i][1], acc[i][2], acc[i][3]);
  }
}

// ---------------------------------------------------------------------------
// helpers for K5
// ---------------------------------------------------------------------------
__device__ __forceinline__ unsigned long long shfl_xor_u64(unsigned long long v,
                                                           int off) {
  const int lo = __shfl_xor((int)(unsigned)(v & 0xFFFFFFFFull), off, 64);
  const int hi = __shfl_xor((int)(unsigned)(v >> 32), off, 64);
  return ((unsigned long long)(unsigned)hi << 32) | (unsigned)lo;
}

// compare-exchange: larger key to lower index (descending)
#define CE8(i, jj)                                                  \
  {                                                                 \
    const unsigned long long ka_ = key[i], kb_ = key[jj];           \
    const bool sw_ = kb_ > ka_;                                     \
    key[i] = sw_ ? kb_ : ka_;                                       \
    key[jj] = sw_ ? ka_ : kb_;                                      \
  }

// ---------------------------------------------------------------------------
// K5: the scan. R15 = R14 + A1 restructured to 16-LANES-PER-SLOT (4 slots per
// wave concurrently). Model (fits R11/R13/R14 evidence): A1 is critical-CHAIN
// bound at a low effective clock; chain/slot-pair = descL(LDS) + L2 loads +
// 6-level ds_bpermute butterfly (~720cy). New layout: each lane owns a
// 16-elem strip -> 4-level butterfly shared by 4 slots (~1Kcy per 4 slots vs
// ~2.4K per 4 before). Register budget protected (R9/R12 lesson): wreg[18]
// dropped (PB reads Wv from L2 like Wg — step-invariant, L2-resident, -72
// VGPR); -e0*mo folded at load so mo dies per-k; g/xp read from LDS only in
// the rare pending branch. Cross-group acc reduce = shfl_xor 16,32 once/step;
// dpart written by group 0. e0 still bit-matches K4's Et. Dot order changes
// (~1e-6 on cur) — same class of reorder as K2-vs-scan already has.
// ---------------------------------------------------------------------------
__global__ __launch_bounds__(1024, 4) void k_scan(
    const float* __restrict__ x, const float* __restrict__ mem0,
    const float* __restrict__ Wv, const float* __restrict__ bv,
    const float* __restrict__ WvWgB, const float* __restrict__ bvg,
    const float* __restrict__ qt, const float* __restrict__ qbk,
    const float* __restrict__ xgp, const float* __restrict__ L0,
    const float* __restrict__ M0, const double* __restrict__ SumE0,
    const float* __restrict__ ctxp, const float* __restrict__ topv,
    const int* __restrict__ topi, float* __restrict__ memcur,
    float* __restrict__ out) {
  const int b = blockIdx.x;
  const int tid = threadIdx.x;
  const int lane = tid & 63;
  const int wvid = tid >> 6;

  __shared__ short tpos[M_];                      // 4 KB
  __shared__ unsigned int descL[NSLOT];           // 1 KB: m | fresh<<11 | pend<<12
  __shared__ __align__(16) float candV[NCAND];    // 2 KB
  __shared__ __align__(16) int candI[NCAND];      // 2 KB
  __shared__ float diffA[NSLOT];                  // 1 KB
  __shared__ float dpart[15][D_];                 // 15 KB
  __shared__ float fpart[15][D_];                 // 15 KB
  __shared__ float fpart2[15][D_];                // 15 KB
  __shared__ float qt_s[2][D_], xt_s[2][D_];      // 4 KB
  __shared__ float CTX0_s[D_], xgp_s[D_], g_s[D_], bv_s[D_], bvg_s[D_];  // 5 KB
  __shared__ float wvlds[(256 - CACHE0) * D_];    // 64 KB
  __shared__ float Msc[S_], qbks[S_];
  __shared__ double sum0s[S_];
  __shared__ float inv_esum;
  __shared__ int Tcount;

  const float4* mem04 = (const float4*)mem0;
  const float4* mcur4c = (const float4*)memcur;
  float4* mcur4 = (float4*)memcur;
  const float4* Wv4 = (const float4*)Wv;
  const float4* Wg4 = (const float4*)WvWgB;
  const float4* qt4 = (const float4*)qt;
  const float4* x4 = (const float4*)x;
  const float4* ctxp4 = (const float4*)ctxp;
  const float4* xgp4 = (const float4*)xgp;
  const float4* wvlds4 = (const float4*)wvlds;

  // ---- one-time preload
  for (int m = tid; m < M_; m += 1024) tpos[m] = -1;
  for (int s = tid; s < NSLOT; s += 1024) descL[s] = 0;
  for (int i = tid; i < (256 - CACHE0) * 64; i += 1024)
    ((float4*)wvlds)[i] = Wg4[(size_t)CACHE0 * 64 + i];
  if (tid < NCAND) {
    candV[tid] = -INFINITY;
    candI[tid] = 0x7FFFFFFF;
  }
  if (tid < S_) {
    Msc[tid] = M0[tid * B_ + b];
    qbks[tid] = qbk[tid * B_ + b];
    sum0s[tid] = SumE0[tid * B_ + b];
  } else if (tid >= 64 && tid < 64 + D_) {
    int d = tid - 64;
    bv_s[d] = bv[d];
    bvg_s[d] = bvg[d];
  } else if (tid >= 512 && tid < 576) {
    int j = tid - 512;
    ((float4*)qt_s[0])[j] = qt4[(size_t)b * 64 + j];  // qt(t=0)
  } else if (tid >= 576 && tid < 640) {
    int j = tid - 576;
    ((float4*)xt_s[0])[j] = x4[(size_t)(b * S_) * 64 + j];  // x(t=0)
  }
  if (tid == 0) Tcount = 0;
  __syncthreads();

  for (int t = 0; t < S_; ++t) {
    const int n = t * B_ + b;
    const int par = t & 1;
    const int Tc = Tcount;
    const float c0 = Msc[t];
    const float qb = qbks[t];

    // ===== A1 (waves 0-14): 16-lane-per-slot, 4 slots per wave concurrent
    if (wvid < 15) {
      const int grp = lane >> 4;  // 0..3: which of 4 concurrent slots
      const int u = lane & 15;    // strip index: elements [u*16, u*16+16)
      // per-step strip of q (used every slot) — 4 float4 in regs
      float4 qr0 = ((const float4*)qt_s[par])[u * 4 + 0];
      float4 qr1 = ((const float4*)qt_s[par])[u * 4 + 1];
      float4 qr2 = ((const float4*)qt_s[par])[u * 4 + 2];
      float4 qr3 = ((const float4*)qt_s[par])[u * 4 + 3];
      float4 acc0 = make_float4(0.f, 0.f, 0.f, 0.f);
      float4 acc1 = acc0, acc2 = acc0, acc3 = acc0;
      const int nown = (Tc > wvid) ? ((Tc - wvid + 14) / 15) : 0;
      for (int j0 = 0; j0 < 17; j0 += 4) {
        if (j0 >= nown) break;
        const int j = j0 + grp;
        const bool act = (j < nown);
        const int s = act ? (wvid + 15 * j) : 0;
        const unsigned int dsc = act ? descL[s] : 0u;
        const int m = dsc & 2047;
        const size_t mobase = (size_t)m * 64 + u * 4;
        const size_t mcbase = (size_t)(b * NSLOT + s) * 64 + u * 4;
        float l0v = 0.f;
        float4 mc0, mc1, mc2, mc3;
        float e0 = 0.f;
        if (act) {
          l0v = L0[(size_t)n * M_ + m];
          const bool fromM0 = (dsc & (1u << 12)) && (dsc & (1u << 11));
          const float4 mo0 = mem04[mobase + 0];
          const float4 mo1 = mem04[mobase + 1];
          const float4 mo2 = mem04[mobase + 2];
          const float4 mo3 = mem04[mobase + 3];
          if (fromM0) {
            mc0 = mo0; mc1 = mo1; mc2 = mo2; mc3 = mo3;
          } else {
            mc0 = mcur4c[mcbase + 0];
            mc1 = mcur4c[mcbase + 1];
            mc2 = mcur4c[mcbase + 2];
            mc3 = mcur4c[mcbase + 3];
          }
          if (dsc & (1u << 12)) {  // pending update (rare): g/xp from LDS
            const float4 g0 = ((const float4*)g_s)[u * 4 + 0];
            const float4 g1 = ((const float4*)g_s)[u * 4 + 1];
            const float4 g2 = ((const float4*)g_s)[u * 4 + 2];
            const float4 g3 = ((const float4*)g_s)[u * 4 + 3];
            const float4 xp0 = ((const float4*)xt_s[par ^ 1])[u * 4 + 0];
            const float4 xp1 = ((const float4*)xt_s[par ^ 1])[u * 4 + 1];
            const float4 xp2 = ((const float4*)xt_s[par ^ 1])[u * 4 + 2];
            const float4 xp3 = ((const float4*)xt_s[par ^ 1])[u * 4 + 3];
            mc0.x = fmaf(g0.x, xp0.x - mc0.x, mc0.x); mc0.y = fmaf(g0.y, xp0.y - mc0.y, mc0.y);
            mc0.z = fmaf(g0.z, xp0.z - mc0.z, mc0.z); mc0.w = fmaf(g0.w, xp0.w - mc0.w, mc0.w);
            mc1.x = fmaf(g1.x, xp1.x - mc1.x, mc1.x); mc1.y = fmaf(g1.y, xp1.y - mc1.y, mc1.y);
            mc1.z = fmaf(g1.z, xp1.z - mc1.z, mc1.z); mc1.w = fmaf(g1.w, xp1.w - mc1.w, mc1.w);
            mc2.x = fmaf(g2.x, xp2.x - mc2.x, mc2.x); mc2.y = fmaf(g2.y, xp2.y - mc2.y, mc2.y);
            mc2.z = fmaf(g2.z, xp2.z - mc2.z, mc2.z); mc2.w = fmaf(g2.w, xp2.w - mc2.w, mc2.w);
            mc3.x = fmaf(g3.x, xp3.x - mc3.x, mc3.x); mc3.y = fmaf(g3.y, xp3.y - mc3.y, mc3.y);
            mc3.z = fmaf(g3.z, xp3.z - mc3.z, mc3.z); mc3.w = fmaf(g3.w, xp3.w - mc3.w, mc3.w);
            mcur4[mcbase + 0] = mc0; mcur4[mcbase + 1] = mc1;
            mcur4[mcbase + 2] = mc2; mcur4[mcbase + 3] = mc3;
            if (u == 0) descL[s] = (unsigned int)m;
          }
          e0 = __expf(l0v - c0);
          // -e0*mo folded here: mo dies before the butterfly
          acc0.x = fmaf(-e0, mo0.x, acc0.x); acc0.y = fmaf(-e0, mo0.y, acc0.y);
          acc0.z = fmaf(-e0, mo0.z, acc0.z); acc0.w = fmaf(-e0, mo0.w, acc0.w);
          acc1.x = fmaf(-e0, mo1.x, acc1.x); acc1.y = fmaf(-e0, mo1.y, acc1.y);
          acc1.z = fmaf(-e0, mo1.z, acc1.z); acc1.w = fmaf(-e0, mo1.w, acc1.w);
          acc2.x = fmaf(-e0, mo2.x, acc2.x); acc2.y = fmaf(-e0, mo2.y, acc2.y);
          acc2.z = fmaf(-e0, mo2.z, acc2.z); acc2.w = fmaf(-e0, mo2.w, acc2.w);
          acc3.x = fmaf(-e0, mo3.x, acc3.x); acc3.y = fmaf(-e0, mo3.y, acc3.y);
          acc3.z = fmaf(-e0, mo3.z, acc3.z); acc3.w = fmaf(-e0, mo3.w, acc3.w);
        } else {
          mc0 = make_float4(0.f, 0.f, 0.f, 0.f);
          mc1 = mc0; mc2 = mc0; mc3 = mc0;
        }
        // per-lane 16-element partial dot
        float p = mc0.x * qr0.x;
        p = fmaf(mc0.y, qr0.y, p); p = fmaf(mc0.z, qr0.z, p); p = fmaf(mc0.w, qr0.w, p);
        p = fmaf(mc1.x, qr1.x, p); p = fmaf(mc1.y, qr1.y, p);
        p = fmaf(mc1.z, qr1.z, p); p = fmaf(mc1.w, qr1.w, p);
        p = fmaf(mc2.x, qr2.x, p); p = fmaf(mc2.y, qr2.y, p);
        p = fmaf(mc2.z, qr2.z, p); p = fmaf(mc2.w, qr2.w, p);
        p = fmaf(mc3.x, qr3.x, p); p = fmaf(mc3.y, qr3.y, p);
        p = fmaf(mc3.z, qr3.z, p); p = fmaf(mc3.w, qr3.w, p);
        // 4-level butterfly within the 16-lane group
#pragma unroll
        for (int off = 1; off < 16; off <<= 1) p += __shfl_xor(p, off, 64);
        const float cur = (p + qb) * 0.0625f;
        const float ce = act ? __expf(cur - c0) : 0.f;
        acc0.x = fmaf(ce, mc0.x, acc0.x); acc0.y = fmaf(ce, mc0.y, acc0.y);
        acc0.z = fmaf(ce, mc0.z, acc0.z); acc0.w = fmaf(ce, mc0.w, acc0.w);
        acc1.x = fmaf(ce, mc1.x, acc1.x); acc1.y = fmaf(ce, mc1.y, acc1.y);
        acc1.z = fmaf(ce, mc1.z, acc1.z); acc1.w = fmaf(ce, mc1.w, acc1.w);
        acc2.x = fmaf(ce, mc2.x, acc2.x); acc2.y = fmaf(ce, mc2.y, acc2.y);
        acc2.z = fmaf(ce, mc2.z, acc2.z); acc2.w = fmaf(ce, mc2.w, acc2.w);
        acc3.x = fmaf(ce, mc3.x, acc3.x); acc3.y = fmaf(ce, mc3.y, acc3.y);
        acc3.z = fmaf(ce, mc3.z, acc3.z); acc3.w = fmaf(ce, mc3.w, acc3.w);
        if (act && u == 0) {
          diffA[s] = ce - e0;
          candV[s] = cur;
          candI[s] = m;
        }
      }
      // cross-group reduction: lanes with equal u across the 4 groups sum up
#pragma unroll
      for (int off = 16; off < 64; off <<= 1) {
        acc0.x += __shfl_xor(acc0.x, off, 64); acc0.y += __shfl_xor(acc0.y, off, 64);
        acc0.z += __shfl_xor(acc0.z, off, 64); acc0.w += __shfl_xor(acc0.w, off, 64);
        acc1.x += __shfl_xor(acc1.x, off, 64); acc1.y += __shfl_xor(acc1.y, off, 64);
        acc1.z += __shfl_xor(acc1.z, off, 64); acc1.w += __shfl_xor(acc1.w, off, 64);
        acc2.x += __shfl_xor(acc2.x, off, 64); acc2.y += __shfl_xor(acc2.y, off, 64);
        acc2.z += __shfl_xor(acc2.z, off, 64); acc2.w += __shfl_xor(acc2.w, off, 64);
        acc3.x += __shfl_xor(acc3.x, off, 64); acc3.y += __shfl_xor(acc3.y, off, 64);
        acc3.z += __shfl_xor(acc3.z, off, 64); acc3.w += __shfl_xor(acc3.w, off, 64);
      }
      if (grp == 0) {
        ((float4*)dpart[wvid])[u * 4 + 0] = acc0;
        ((float4*)dpart[wvid])[u * 4 + 1] = acc1;
        ((float4*)dpart[wvid])[u * 4 + 2] = acc2;
        ((float4*)dpart[wvid])[u * 4 + 3] = acc3;
      }
    } else {
      // wave 15: candidate prep + per-step prefetches
#pragma unroll
      for (int jj = 0; jj < 4; ++jj) {
        const int j = lane + jj * 64;
        const int ii = topi[n * TOPC + j];
        const bool fresh = (tpos[ii] < 0);
        candV[NSLOT + j] = fresh ? topv[n * TOPC + j] : -INFINITY;
        candI[NSLOT + j] = fresh ? ii : 0x7FFFFFFF;
      }
      const float4 c0v = ctxp4[(size_t)(0 * N_ + n) * 64 + lane];
      const float4 c1v = ctxp4[(size_t)(1 * N_ + n) * 64 + lane];
      const float4 c2v = ctxp4[(size_t)(2 * N_ + n) * 64 + lane];
      const float4 c3v = ctxp4[(size_t)(3 * N_ + n) * 64 + lane];
      ((float4*)CTX0_s)[lane] = make_float4(c0v.x + c1v.x + c2v.x + c3v.x,
                                            c0v.y + c1v.y + c2v.y + c3v.y,
                                            c0v.z + c1v.z + c2v.z + c3v.z,
                                            c0v.w + c1v.w + c2v.w + c3v.w);
      ((float4*)xgp_s)[lane] = xgp4[(size_t)n * 64 + lane];
      if (t + 1 < S_) {
        ((float4*)qt_s[par ^ 1])[lane] = qt4[(size_t)(n + B_) * 64 + lane];
        ((float4*)xt_s[par ^ 1])[lane] = x4[(size_t)(b * S_ + t + 1) * 64 + lane];
      }
    }
    __syncthreads();  // B1

    // ===== PB: GEMV + denom (waves 0-14) || top-8 selection (wave 15)
    if (wvid < 15) {
      const int kbase = 17 * wvid;
      const int nr = (wvid == 14) ? 18 : 17;
      float mynum = 0.f;
      if (lane < nr) {
        const int k = (lane == 17) ? 255 : (kbase + lane);
        float nv = CTX0_s[k];
#pragma unroll
        for (int p = 0; p < 15; ++p) nv += dpart[p][k];
        mynum = nv;
      }
      float4 a1 = make_float4(0.f, 0.f, 0.f, 0.f);
      float4 a2 = make_float4(0.f, 0.f, 0.f, 0.f);
#pragma unroll
      for (int j = 0; j < 17; ++j) {
        const float nv = __int_as_float(__builtin_amdgcn_readlane(__float_as_int(mynum), j));
        const int r = kbase + j;
        const float4 wv4 = Wv4[(size_t)r * 64 + lane];  // L2-resident, step-invariant
        a1.x = fmaf(nv, wv4.x, a1.x); a1.y = fmaf(nv, wv4.y, a1.y);
        a1.z = fmaf(nv, wv4.z, a1.z); a1.w = fmaf(nv, wv4.w, a1.w);
        const float4 w4 = (r >= CACHE0) ? wvlds4[(size_t)(r - CACHE0) * 64 + lane]
                                        : Wg4[(size_t)r * 64 + lane];
        a2.x = fmaf(nv, w4.x, a2.x); a2.y = fmaf(nv, w4.y, a2.y);
        a2.z = fmaf(nv, w4.z, a2.z); a2.w = fmaf(nv, w4.w, a2.w);
      }
      if (wvid == 14) {
        const float nv = __int_as_float(__builtin_amdgcn_readlane(__float_as_int(mynum), 17));
        const float4 wv4 = Wv4[(size_t)255 * 64 + lane];
        a1.x = fmaf(nv, wv4.x, a1.x); a1.y = fmaf(nv, wv4.y, a1.y);
        a1.z = fmaf(nv, wv4.z, a1.z); a1.w = fmaf(nv, wv4.w, a1.w);
        const float4 w4 = wvlds4[(size_t)(255 - CACHE0) * 64 + lane];
        a2.x = fmaf(nv, w4.x, a2.x); a2.y = fmaf(nv, w4.y, a2.y);
        a2.z = fmaf(nv, w4.z, a2.z); a2.w = fmaf(nv, w4.w, a2.w);
      }
      ((float4*)fpart[wvid])[lane] = a1;
      ((float4*)fpart2[wvid])[lane] = a2;
      if (wvid == 0) {  // denominator (wave 0: GEMV is shorter than selection)
        double dsum = 0.0;
        for (int s2 = lane; s2 < Tc; s2 += 64) dsum += (double)diffA[s2];
#pragma unroll
        for (int off = 32; off > 0; off >>= 1) dsum += __shfl_down(dsum, off, 64);
        if (lane == 0) inv_esum = (float)(1.0 / (sum0s[t] + dsum));
      }
    } else if (t + 1 < S_) {
      // ---- wave 15: top-8 of 512 candidates via bitonic top-k merge.
      // key = sortable(float) << 11 | (2047 - idx): order == (v desc, idx asc)
      const float4 cv0 = ((const float4*)candV)[lane * 2];
      const float4 cv1 = ((const float4*)candV)[lane * 2 + 1];
      const int4 ci0 = ((const int4*)candI)[lane * 2];
      const int4 ci1 = ((const int4*)candI)[lane * 2 + 1];
      unsigned long long key[8];
      {
        const float vs[8] = {cv0.x, cv0.y, cv0.z, cv0.w, cv1.x, cv1.y, cv1.z, cv1.w};
        const int is[8] = {ci0.x, ci0.y, ci0.z, ci0.w, ci1.x, ci1.y, ci1.z, ci1.w};
#pragma unroll
        for (int j = 0; j < 8; ++j) {
          unsigned int bits = __float_as_uint(vs[j]);
          bits = (bits & 0x80000000u) ? ~bits : (bits | 0x80000000u);
          key[j] = ((unsigned long long)bits << 11) |
                   (unsigned long long)(2047 - (is[j] & 2047));
        }
      }
      // per-lane sort-8 desc (Batcher odd-even mergesort, 19 CE)
      CE8(0, 1) CE8(2, 3) CE8(4, 5) CE8(6, 7)
      CE8(0, 2) CE8(1, 3) CE8(4, 6) CE8(5, 7)
      CE8(1, 2) CE8(5, 6)
      CE8(0, 4) CE8(1, 5) CE8(2, 6) CE8(3, 7)
      CE8(2, 4) CE8(3, 5)
      CE8(1, 2) CE8(3, 4) CE8(5, 6)
      // 6-level butterfly: keep-top-8 merge (max(a[i], b[7-i]) is bitonic),
      // then 12-CE bitonic cleanup back to descending
#pragma unroll
      for (int off = 1; off < 64; off <<= 1) {
        unsigned long long pk[8];
#pragma unroll
        for (int j = 0; j < 8; ++j) pk[j] = shfl_xor_u64(key[7 - j], off);
#pragma unroll
        for (int j = 0; j < 8; ++j) key[j] = (pk[j] > key[j]) ? pk[j] : key[j];
        CE8(0, 4) CE8(1, 5) CE8(2, 6) CE8(3, 7)
        CE8(0, 2) CE8(1, 3) CE8(4, 6) CE8(5, 7)
        CE8(0, 1) CE8(2, 3) CE8(4, 5) CE8(6, 7)
      }
      // all lanes now hold the identical top-8 list; lane r takes rank r
      int myM = 2047 - (int)(key[0] & 2047);
#pragma unroll
      for (int r = 1; r < TK; ++r) {
        const int mr = 2047 - (int)(key[r] & 2047);
        if (lane == r) myM = mr;
      }
      int sOld = 0;
      bool fresh = false;
      if (lane < TK) {
        sOld = (int)tpos[myM];
        fresh = sOld < 0;
      }
      const unsigned long long fm = __ballot(fresh);
      if (lane < TK) {
        const int before = (int)__popcll(fm & ((1ull << lane) - 1ull));
        const int snew = fresh ? (Tc + before) : sOld;
        if (fresh) {
          tpos[myM] = (short)snew;
          candI[snew] = myM;
        }
        descL[snew] = (unsigned int)myM | ((fresh ? 1u : 0u) << 11) | (1u << 12);
      }
      if (lane == 0) Tcount = Tc + (int)__popcll(fm);
    }
    __syncthreads();  // B2

    // ===== PC: finalize out & gate =====
    if (tid < D_) {
      float o = 0.f;
#pragma unroll
      for (int p = 0; p < 15; ++p) o += fpart[p][tid];
      o = o * inv_esum + bv_s[tid];
      out[((size_t)b * S_ + t) * D_ + tid] = o;
    } else if (tid < 2 * D_) {
      const int d = tid - D_;
      float gg = 0.f;
#pragma unroll
      for (int p = 0; p < 15; ++p) gg += fpart2[p][d];
      const float gin = xgp_s[d] + gg * inv_esum + bvg_s[d];
      g_s[d] = 1.0f / (1.0f + __expf(-gin));
    }
    __syncthreads();  // B3
  }
}

// ---------------------------------------------------------------------------
extern "C" void kernel_launch(void* const* d_in, const int* in_sizes, int n_in,
                              void* d_out, int out_size, void* d_ws, size_t ws_size,
                              hipStream_t stream) {
  const float* x = (const float*)d_in[0];
  const float* mem0 = (const float*)d_in[1];
  const float* Wq = (const float*)d_in[2];
  const float* bq = (const float*)d_in[3];
  const float* Wk = (const float*)d_in[4];
  const float* bk = (const float*)d_in[5];
  const float* Wv = (const float*)d_in[6];
  const float* bv = (const float*)d_in[7];
  const float* Wg = (const float*)d_in[8];
  const float* bg = (const float*)d_in[9];
  float* out = (float*)d_out;
  float* ws = (float*)d_ws;

  size_t o = 0;
  float* WkT = ws + o;    o += (size_t)D_ * D_;
  float* qt = ws + o;     o += (size_t)N_ * D_;
  float* qbk = ws + o;    o += N_;
  float* xgp = ws + o;    o += (size_t)N_ * D_;
  float* L0 = ws + o;     o += (size_t)N_ * M_;
  float* M0 = ws + o;     o += N_;
  double* SumE0 = (double*)(ws + o); o += 2 * N_;
  float* ctxp = ws + o;   o += (size_t)KSPLIT * N_ * D_;
  float* topv = ws + o;   o += (size_t)N_ * TOPC;
  int* topi = (int*)(ws + o); o += (size_t)N_ * TOPC;
  float* WvWgB = ws + o;  o += (size_t)D_ * D_;
  float* bvg = ws + o;    o += D_;
  float* memcur = ws + o; o += (size_t)B_ * NSLOT * D_;

  k_wvwgT<<<dim3(81), dim3(256), 0, stream>>>(Wv, Wg, bv, bg, Wk, WvWgB, bvg, WkT);
  k_qproj<<<dim3(N_), dim3(256), 0, stream>>>(x, Wq, bq, bk, WkT, Wg, qt, qbk, xgp);
  k_L0<<<dim3(M_ / 64, N_ / 64), dim3(256), 0, stream>>>(qt, mem0, qbk, L0);
  k_sortstats<<<dim3(N_), dim3(1024), 0, stream>>>(L0, topv, topi, M0, SumE0);
  k_ctxpart<<<dim3(KSPLIT, N_ / 32, D_ / 64), dim3(256), 0, stream>>>(L0, M0, mem0, ctxp);
  k_scan<<<dim3(B_), dim3(1024), 0, stream>>>(x, mem0, Wv, bv, WvWgB, bvg, qt, qbk, xgp,
                                              L0, M0, SumE0, ctxp, topv, topi, memcur, out);
}

// Round 9
// 594.804 us; speedup vs baseline: 1.1571x; 1.1571x over previous
//
#include <hip/hip_runtime.h>
#include <math.h>

// Problem constants
constexpr int B_ = 8, S_ = 32, D_ = 256, M_ = 2048;
constexpr int N_ = S_ * B_;          // 256 (t,b) pairs, n = t*B + b
constexpr int TK = 8;                // TOPK
constexpr int NSLOT = 256;           // max distinct touched rows (8*31=248)
constexpr int TOPC = 256;            // precomputed top-C of L0 per (t,b)
constexpr int NCAND = NSLOT + TOPC;  // 512
constexpr int KSPLIT = 4;            // ctxpart split-K
constexpr int CACHE0 = 192;          // WvWgB rows [CACHE0,256) cached in LDS (64KB)

// ---------------------------------------------------------------------------
// K0: blocks 0..15: WvWgB[i][d] = sum_j Wv[i][j]*Wg[D+j][d]
//     block 16:     bvg[d] = bg[d] + sum_j bv[j]*Wg[D+j][d]
//     blocks 17..80: WkT[j][i] = Wk[i][j]
// ---------------------------------------------------------------------------
__global__ __launch_bounds__(256) void k_wvwgT(const float* __restrict__ Wv,
                                               const float* __restrict__ Wg,
                                               const float* __restrict__ bv,
                                               const float* __restrict__ bg,
                                               const float* __restrict__ Wk,
                                               float* __restrict__ WvWgB,
                                               float* __restrict__ bvg,
                                               float* __restrict__ WkT) {
  int blk = blockIdx.x;
  int tid = threadIdx.x;
  if (blk >= 17) {
    __shared__ float tile[32][33];
    int bb = blk - 17;
    int bx = bb & 7, by = bb >> 3;
    int x0 = bx * 32, y0 = by * 32;
    int tx = tid & 31, ty = tid >> 5;
    for (int j = ty; j < 32; j += 8) tile[j][tx] = Wk[(y0 + j) * D_ + x0 + tx];
    __syncthreads();
    for (int j = ty; j < 32; j += 8) WkT[(x0 + j) * D_ + y0 + tx] = tile[tx][j];
    return;
  }
  if (blk == 16) {
    float a = bg[tid];
#pragma unroll 8
    for (int j = 0; j < D_; ++j) a = fmaf(bv[j], Wg[(size_t)(D_ + j) * D_ + tid], a);
    bvg[tid] = a;
    return;
  }
  int i0 = (blk & 3) * 64, d0 = (blk >> 2) * 64;
  __shared__ float At[64 * 64];  // [j][i]
  __shared__ float Bt[64 * 64];  // [j][d]
  const int r = tid & 63, c = tid >> 6;
  const int lane = tid & 63, wvv = tid >> 6;
  const int tx = lane & 15, ty = lane >> 4;
  const int dg = tx * 4, ig = (wvv * 4 + ty) * 4;
  float acc[4][4];
#pragma unroll
  for (int i = 0; i < 4; ++i)
#pragma unroll
    for (int j = 0; j < 4; ++j) acc[i][j] = 0.f;
  for (int kc = 0; kc < 4; ++kc) {
    __syncthreads();
#pragma unroll
    for (int it = 0; it < 4; ++it) {
      int jq = (c * 4 + it) * 4;
      float4 a = *(const float4*)&Wv[(i0 + r) * D_ + kc * 64 + jq];
      At[(jq + 0) * 64 + r] = a.x; At[(jq + 1) * 64 + r] = a.y;
      At[(jq + 2) * 64 + r] = a.z; At[(jq + 3) * 64 + r] = a.w;
      *(float4*)&Bt[r * 64 + jq] =
          *(const float4*)&Wg[(size_t)(D_ + kc * 64 + r) * D_ + d0 + jq];
    }
    __syncthreads();
#pragma unroll 4
    for (int j = 0; j < 64; ++j) {
      float4 av = *(const float4*)&At[j * 64 + ig];
      float4 bv4 = *(const float4*)&Bt[j * 64 + dg];
      acc[0][0] = fmaf(av.x, bv4.x, acc[0][0]); acc[0][1] = fmaf(av.x, bv4.y, acc[0][1]);
      acc[0][2] = fmaf(av.x, bv4.z, acc[0][2]); acc[0][3] = fmaf(av.x, bv4.w, acc[0][3]);
      acc[1][0] = fmaf(av.y, bv4.x, acc[1][0]); acc[1][1] = fmaf(av.y, bv4.y, acc[1][1]);
      acc[1][2] = fmaf(av.y, bv4.z, acc[1][2]); acc[1][3] = fmaf(av.y, bv4.w, acc[1][3]);
      acc[2][0] = fmaf(av.z, bv4.x, acc[2][0]); acc[2][1] = fmaf(av.z, bv4.y, acc[2][1]);
      acc[2][2] = fmaf(av.z, bv4.z, acc[2][2]); acc[2][3] = fmaf(av.z, bv4.w, acc[2][3]);
      acc[3][0] = fmaf(av.w, bv4.x, acc[3][0]); acc[3][1] = fmaf(av.w, bv4.y, acc[3][1]);
      acc[3][2] = fmaf(av.w, bv4.z, acc[3][2]); acc[3][3] = fmaf(av.w, bv4.w, acc[3][3]);
    }
  }
#pragma unroll
  for (int i = 0; i < 4; ++i)
    *(float4*)&WvWgB[(size_t)(i0 + ig + i) * D_ + d0 + dg] =
        make_float4(acc[i][0], acc[i][1], acc[i][2], acc[i][3]);
}

// ---------------------------------------------------------------------------
// K1: per n=(t,b): q = xt@Wq+bq ; qt[d]=sum_i q[i]*WkT[i][d] ; qbk = q.bk ;
//     xgpre = xt @ Wg[0:D,:]
// ---------------------------------------------------------------------------
__global__ __launch_bounds__(256) void k_qproj(
    const float* __restrict__ x, const float* __restrict__ Wq,
    const float* __restrict__ bq, const float* __restrict__ bk,
    const float* __restrict__ WkT, const float* __restrict__ Wg,
    float* __restrict__ qt, float* __restrict__ qbk, float* __restrict__ xgp) {
  int n = blockIdx.x, tid = threadIdx.x;
  int t = n / B_, b = n % B_;
  __shared__ float xr[D_], qsh[D_];
  __shared__ float red[4];
  xr[tid] = x[(b * S_ + t) * D_ + tid];
  __syncthreads();
  float accq = bq[tid], accg = 0.f;
#pragma unroll 8
  for (int i = 0; i < D_; ++i) {
    float xv = xr[i];
    accq = fmaf(xv, Wq[i * D_ + tid], accq);
    accg = fmaf(xv, Wg[i * D_ + tid], accg);
  }
  qsh[tid] = accq;
  xgp[n * D_ + tid] = accg;
  float p = accq * bk[tid];
  for (int off = 32; off > 0; off >>= 1) p += __shfl_down(p, off, 64);
  if ((tid & 63) == 0) red[tid >> 6] = p;
  __syncthreads();
  float acct = 0.f;
#pragma unroll 8
  for (int i = 0; i < D_; ++i) acct = fmaf(qsh[i], WkT[i * D_ + tid], acct);
  qt[n * D_ + tid] = acct;
  if (tid == 0) qbk[n] = red[0] + red[1] + red[2] + red[3];
}

// ---------------------------------------------------------------------------
// K2: L0[n][m] = (memory[m] . qt[n] + qbk[n]) / 16
// ---------------------------------------------------------------------------
__global__ __launch_bounds__(256) void k_L0(
    const float* __restrict__ qt, const float* __restrict__ mem,
    const float* __restrict__ qbk, float* __restrict__ L0) {
  __shared__ float qtT[64 * 64];
  __shared__ float mT[64 * 64];
  const int tid = threadIdx.x;
  const int m0 = blockIdx.x * 64, n0 = blockIdx.y * 64;
  const int r = tid & 63, c = tid >> 6;
  const int lane = tid & 63, wv = tid >> 6;
  const int tx = lane & 15, ty = lane >> 4;
  const int mg = tx * 4, ng = (wv * 4 + ty) * 4;
  float acc[4][4];
#pragma unroll
  for (int i = 0; i < 4; ++i)
#pragma unroll
    for (int j = 0; j < 4; ++j) acc[i][j] = 0.f;
  for (int kc = 0; kc < 4; ++kc) {
    __syncthreads();
#pragma unroll
    for (int it = 0; it < 4; ++it) {
      int kq = (c * 4 + it) * 4;
      float4 a = *(const float4*)&qt[(n0 + r) * D_ + kc * 64 + kq];
      qtT[(kq + 0) * 64 + r] = a.x; qtT[(kq + 1) * 64 + r] = a.y;
      qtT[(kq + 2) * 64 + r] = a.z; qtT[(kq + 3) * 64 + r] = a.w;
      float4 bm = *(const float4*)&mem[(m0 + r) * D_ + kc * 64 + kq];
      mT[(kq + 0) * 64 + r] = bm.x; mT[(kq + 1) * 64 + r] = bm.y;
      mT[(kq + 2) * 64 + r] = bm.z; mT[(kq + 3) * 64 + r] = bm.w;
    }
    __syncthreads();
#pragma unroll 4
    for (int k = 0; k < 64; ++k) {
      float4 av = *(const float4*)&qtT[k * 64 + ng];
      float4 bv4 = *(const float4*)&mT[k * 64 + mg];
      acc[0][0] = fmaf(av.x, bv4.x, acc[0][0]); acc[0][1] = fmaf(av.x, bv4.y, acc[0][1]);
      acc[0][2] = fmaf(av.x, bv4.z, acc[0][2]); acc[0][3] = fmaf(av.x, bv4.w, acc[0][3]);
      acc[1][0] = fmaf(av.y, bv4.x, acc[1][0]); acc[1][1] = fmaf(av.y, bv4.y, acc[1][1]);
      acc[1][2] = fmaf(av.y, bv4.z, acc[1][2]); acc[1][3] = fmaf(av.y, bv4.w, acc[1][3]);
      acc[2][0] = fmaf(av.z, bv4.x, acc[2][0]); acc[2][1] = fmaf(av.z, bv4.y, acc[2][1]);
      acc[2][2] = fmaf(av.z, bv4.z, acc[2][2]); acc[2][3] = fmaf(av.z, bv4.w, acc[2][3]);
      acc[3][0] = fmaf(av.w, bv4.x, acc[3][0]); acc[3][1] = fmaf(av.w, bv4.y, acc[3][1]);
      acc[3][2] = fmaf(av.w, bv4.z, acc[3][2]); acc[3][3] = fmaf(av.w, bv4.w, acc[3][3]);
    }
  }
#pragma unroll
  for (int i = 0; i < 4; ++i) {
    int n = n0 + ng + i;
    float qbv = qbk[n];
    float4 o;
    o.x = (acc[i][0] + qbv) * 0.0625f; o.y = (acc[i][1] + qbv) * 0.0625f;
    o.z = (acc[i][2] + qbv) * 0.0625f; o.w = (acc[i][3] + qbv) * 0.0625f;
    *(float4*)&L0[n * M_ + m0 + mg] = o;
  }
}

// ---------------------------------------------------------------------------
// K3: fused full bitonic sort (desc, tie idx asc) + top-256 + M0 + SumE0(fp64)
// __expf for the exp-sum (feeds SumE0; matches k_ctxpart/k_scan's __expf).
// ---------------------------------------------------------------------------
__global__ __launch_bounds__(1024) void k_sortstats(const float* __restrict__ L0,
                                                    float* __restrict__ topv,
                                                    int* __restrict__ topi,
                                                    float* __restrict__ M0,
                                                    double* __restrict__ SumE0) {
  int n = blockIdx.x, tid = threadIdx.x;
  __shared__ float v[M_];
  __shared__ short ix[M_];
  __shared__ double redd[16];
  for (int m = tid; m < M_; m += 1024) {
    v[m] = L0[(size_t)n * M_ + m];
    ix[m] = (short)m;
  }
  __syncthreads();
  for (int size = 2; size <= M_; size <<= 1) {
    for (int stride = size >> 1; stride > 0; stride >>= 1) {
      const int i = tid;  // exactly M_/2 pairs
      const int pos = 2 * i - (i & (stride - 1));
      const int j = pos + stride;
      const bool desc = ((pos & size) == 0);
      const float va = v[pos], vb2 = v[j];
      const short ia = ix[pos], ib = ix[j];
      const bool aG = (va > vb2) || (va == vb2 && ia < ib);
      if (desc ? !aG : aG) { v[pos] = vb2; v[j] = va; ix[pos] = ib; ix[j] = ia; }
      __syncthreads();
    }
  }
  if (tid < TOPC) {
    topv[n * TOPC + tid] = v[tid];
    topi[n * TOPC + tid] = (int)ix[tid];
  }
  float mx = v[0];
  if (tid == 0) M0[n] = mx;
  double s = 0.0;
  for (int m = tid; m < M_; m += 1024) s += (double)__expf(v[m] - mx);
  for (int off = 32; off > 0; off >>= 1) s += __shfl_down(s, off, 64);
  if ((tid & 63) == 0) redd[tid >> 6] = s;
  __syncthreads();
  if (tid == 0) {
    double t = 0.0;
#pragma unroll
    for (int w = 0; w < 16; ++w) t += redd[w];
    SumE0[n] = t;
  }
}

// ---------------------------------------------------------------------------
// K4: ctxpart[ks][n][d] = sum over ks's K-range of exp(L0-M0)*memory (split-4)
// __expf: bit-matches k_scan A1's e0 (same args, same intrinsic) so the
// correction cancellation is exact.
// ---------------------------------------------------------------------------
__global__ __launch_bounds__(256) void k_ctxpart(
    const float* __restrict__ L0, const float* __restrict__ M0,
    const float* __restrict__ mem, float* __restrict__ ctxp) {
  int ks = blockIdx.x;
  int n0 = blockIdx.y * 32;
  int d0 = blockIdx.z * 64;
  int tid = threadIdx.x;
  __shared__ float Et[64 * 32];
  __shared__ float mTl[64 * 64];
  __shared__ float Msh[32];
  if (tid < 32) Msh[tid] = M0[n0 + tid];
  const int lane = tid & 63, wv = tid >> 6;
  const int tx = lane & 15, ty = lane >> 4;
  const int ng = (wv * 4 + ty) * 2;
  const int dg = tx * 4;
  float acc[2][4] = {{0, 0, 0, 0}, {0, 0, 0, 0}};
  for (int kc = 0; kc < 8; ++kc) {
    int kb = ks * 512 + kc * 64;
    __syncthreads();
#pragma unroll
    for (int j = 0; j < 8; ++j) {
      int ii = tid + 256 * j;
      int nr = ii & 31, kk = ii >> 5;
      Et[kk * 32 + nr] = __expf(L0[(n0 + nr) * M_ + kb + kk] - Msh[nr]);
    }
    {
      int r = tid & 63, c = tid >> 6;
#pragma unroll
      for (int j = 0; j < 4; ++j) {
        int c4 = (c * 4 + j) * 4;
        *(float4*)&mTl[r * 64 + c4] = *(const float4*)&mem[(kb + r) * D_ + d0 + c4];
      }
    }
    __syncthreads();
#pragma unroll 4
    for (int kk = 0; kk < 64; ++kk) {
      float4 mv = *(const float4*)&mTl[kk * 64 + dg];
      float e0v = Et[kk * 32 + ng], e1v = Et[kk * 32 + ng + 1];
      acc[0][0] = fmaf(e0v, mv.x, acc[0][0]); acc[0][1] = fmaf(e0v, mv.y, acc[0][1]);
      acc[0][2] = fmaf(e0v, mv.z, acc[0][2]); acc[0][3] = fmaf(e0v, mv.w, acc[0][3]);
      acc[1][0] = fmaf(e1v, mv.x, acc[1][0]); acc[1][1] = fmaf(e1v, mv.y, acc[1][1]);
      acc[1][2] = fmaf(e1v, mv.z, acc[1][2]); acc[1][3] = fmaf(e1v, mv.w, acc[1][3]);
    }
  }
#pragma unroll
  for (int i = 0; i < 2; ++i) {
    int n = n0 + ng + i;
    *(float4*)&ctxp[((size_t)ks * N_ + n) * D_ + d0 + dg] =
        make_float4(acc[i][0], acc[i][1], acc[i][2], acc[i][3]);
  }
}

// ---------------------------------------------------------------------------
// helpers for K5
// ---------------------------------------------------------------------------
__device__ __forceinline__ unsigned long long shfl_xor_u64(unsigned long long v,
                                                           int off) {
  const int lo = __shfl_xor((int)(unsigned)(v & 0xFFFFFFFFull), off, 64);
  const int hi = __shfl_xor((int)(unsigned)(v >> 32), off, 64);
  return ((unsigned long long)(unsigned)hi << 32) | (unsigned)lo;
}

// compare-exchange: larger key to lower index (descending)
#define CE8(i, jj)                                                  \
  {                                                                 \
    const unsigned long long ka_ = key[i], kb_ = key[jj];           \
    const bool sw_ = kb_ > ka_;                                     \
    key[i] = sw_ ? kb_ : ka_;                                       \
    key[jj] = sw_ ? ka_ : kb_;                                      \
  }

// ---------------------------------------------------------------------------
// K5: the scan. R16 = exact revert to R14 (best measured: k_scan 427us,
// total 597.5us). R15's 16-lane-per-slot layout fired both tripwires:
// 32-way LDS bank conflicts on the u*64-byte strip reads (SQ_LDS_BANK_
// CONFLICT 9K->324K) and register spills (WRITE_SIZE +784KB). Session
// verdict after R9-R15: A1's step time is a latency-structure floor (HBM
// 0.24%, VALU 0.5% — not a hardware roofline); barrier-count, shuffle-
// latency, issue-width and instruction-count hypotheses all tested; only
// expf->__expf (-5us) survived. Structure: R8 core (depth-1 pipelined,
// register-resident, batch-2 from R13) + R9's bitonic top-8 selection +
// denom on wave 0 + __expf everywhere.
// ---------------------------------------------------------------------------
__global__ __launch_bounds__(1024, 4) void k_scan(
    const float* __restrict__ x, const float* __restrict__ mem0,
    const float* __restrict__ Wv, const float* __restrict__ bv,
    const float* __restrict__ WvWgB, const float* __restrict__ bvg,
    const float* __restrict__ qt, const float* __restrict__ qbk,
    const float* __restrict__ xgp, const float* __restrict__ L0,
    const float* __restrict__ M0, const double* __restrict__ SumE0,
    const float* __restrict__ ctxp, const float* __restrict__ topv,
    const int* __restrict__ topi, float* __restrict__ memcur,
    float* __restrict__ out) {
  const int b = blockIdx.x;
  const int tid = threadIdx.x;
  const int lane = tid & 63;
  const int wvid = tid >> 6;

  __shared__ short tpos[M_];                      // 4 KB
  __shared__ unsigned int descL[NSLOT];           // 1 KB: m | fresh<<11 | pend<<12
  __shared__ __align__(16) float candV[NCAND];    // 2 KB
  __shared__ __align__(16) int candI[NCAND];      // 2 KB
  __shared__ float diffA[NSLOT];                  // 1 KB
  __shared__ float dpart[15][D_];                 // 15 KB
  __shared__ float fpart[15][D_];                 // 15 KB
  __shared__ float fpart2[15][D_];                // 15 KB
  __shared__ float qt_s[2][D_], xt_s[2][D_];      // 4 KB
  __shared__ float CTX0_s[D_], xgp_s[D_], g_s[D_], bv_s[D_], bvg_s[D_];  // 5 KB
  __shared__ float wvlds[(256 - CACHE0) * D_];    // 64 KB
  __shared__ float Msc[S_], qbks[S_];
  __shared__ double sum0s[S_];
  __shared__ float inv_esum;
  __shared__ int Tcount;

  const float4* mem04 = (const float4*)mem0;
  const float4* mcur4c = (const float4*)memcur;
  float4* mcur4 = (float4*)memcur;
  const float4* Wv4 = (const float4*)Wv;
  const float4* Wg4 = (const float4*)WvWgB;
  const float4* qt4 = (const float4*)qt;
  const float4* x4 = (const float4*)x;
  const float4* ctxp4 = (const float4*)ctxp;
  const float4* xgp4 = (const float4*)xgp;
  const float4* wvlds4 = (const float4*)wvlds;

  // ---- pinned Wv strip: wave w (w<15) holds rows [17w, 17w+17) (+row 255 for w=14)
  float4 wreg[18];
  {
    const int kbase = 17 * wvid;
    if (wvid < 15) {
#pragma unroll
      for (int j = 0; j < 17; ++j) wreg[j] = Wv4[(size_t)(kbase + j) * 64 + lane];
      wreg[17] = (wvid == 14) ? Wv4[(size_t)255 * 64 + lane] : wreg[16];
    }
  }

  // ---- one-time preload
  for (int m = tid; m < M_; m += 1024) tpos[m] = -1;
  for (int s = tid; s < NSLOT; s += 1024) descL[s] = 0;
  for (int i = tid; i < (256 - CACHE0) * 64; i += 1024)
    ((float4*)wvlds)[i] = Wg4[(size_t)CACHE0 * 64 + i];
  if (tid < NCAND) {
    candV[tid] = -INFINITY;
    candI[tid] = 0x7FFFFFFF;
  }
  if (tid < S_) {
    Msc[tid] = M0[tid * B_ + b];
    qbks[tid] = qbk[tid * B_ + b];
    sum0s[tid] = SumE0[tid * B_ + b];
  } else if (tid >= 64 && tid < 64 + D_) {
    int d = tid - 64;
    bv_s[d] = bv[d];
    bvg_s[d] = bvg[d];
  } else if (tid >= 512 && tid < 576) {
    int j = tid - 512;
    ((float4*)qt_s[0])[j] = qt4[(size_t)b * 64 + j];  // qt(t=0)
  } else if (tid >= 576 && tid < 640) {
    int j = tid - 576;
    ((float4*)xt_s[0])[j] = x4[(size_t)(b * S_) * 64 + j];  // x(t=0)
  }
  if (tid == 0) Tcount = 0;
  __syncthreads();

  for (int t = 0; t < S_; ++t) {
    const int n = t * B_ + b;
    const int par = t & 1;
    const int Tc = Tcount;
    const float c0 = Msc[t];
    const float qb = qbks[t];

    // ===== A1 (waves 0-14): batch-2 lazy-update + slot-dots + correction
    if (wvid < 15) {
      const float4 qv = ((const float4*)qt_s[par])[lane];
      const float4 g4 = ((const float4*)g_s)[lane];
      const float4 xpv = ((const float4*)xt_s[par ^ 1])[lane];
      float4 acc = make_float4(0.f, 0.f, 0.f, 0.f);
      const int nown = (Tc > wvid) ? ((Tc - wvid + 14) / 15) : 0;
      for (int j0 = 0; j0 < 17; j0 += 2) {
        if (j0 >= nown) break;
        const bool v1 = (j0 + 1) < nown;
        const int s0 = wvid + 15 * j0;
        const int s1 = s0 + 15;
        // --- load pass: issue both slots' loads together
        const unsigned int dsc0 = descL[s0];
        const unsigned int dsc1 = v1 ? descL[s1] : 0u;
        const int m0i = dsc0 & 2047;
        const int m1i = dsc1 & 2047;
        const float4 mo0 = mem04[(size_t)m0i * 64 + lane];
        const float4 mo1 = v1 ? mem04[(size_t)m1i * 64 + lane]
                              : make_float4(0.f, 0.f, 0.f, 0.f);
        const float l00 = L0[(size_t)n * M_ + m0i];
        const float l01 = v1 ? L0[(size_t)n * M_ + m1i] : 0.f;
        const bool fM0 = (dsc0 & (1u << 12)) && (dsc0 & (1u << 11));
        const bool fM1 = (dsc1 & (1u << 12)) && (dsc1 & (1u << 11));
        float4 mc0 = fM0 ? mo0 : mcur4c[(size_t)(b * NSLOT + s0) * 64 + lane];
        float4 mc1 = v1 ? (fM1 ? mo1 : mcur4c[(size_t)(b * NSLOT + s1) * 64 + lane])
                        : make_float4(0.f, 0.f, 0.f, 0.f);
        // --- update+writeback+correction+partial dot: mo/l0 die here
        if (dsc0 & (1u << 12)) {
          mc0.x = fmaf(g4.x, xpv.x - mc0.x, mc0.x);
          mc0.y = fmaf(g4.y, xpv.y - mc0.y, mc0.y);
          mc0.z = fmaf(g4.z, xpv.z - mc0.z, mc0.z);
          mc0.w = fmaf(g4.w, xpv.w - mc0.w, mc0.w);
          mcur4[(size_t)(b * NSLOT + s0) * 64 + lane] = mc0;
          if (lane == 0) descL[s0] = (unsigned int)m0i;
        }
        const float e00 = __expf(l00 - c0);
        acc.x = fmaf(-e00, mo0.x, acc.x);
        acc.y = fmaf(-e00, mo0.y, acc.y);
        acc.z = fmaf(-e00, mo0.z, acc.z);
        acc.w = fmaf(-e00, mo0.w, acc.w);
        float p0 = mc0.x * qv.x;
        p0 = fmaf(mc0.y, qv.y, p0);
        p0 = fmaf(mc0.z, qv.z, p0);
        p0 = fmaf(mc0.w, qv.w, p0);
        float p1 = 0.f, e01 = 0.f;
        if (v1) {
          if (dsc1 & (1u << 12)) {
            mc1.x = fmaf(g4.x, xpv.x - mc1.x, mc1.x);
            mc1.y = fmaf(g4.y, xpv.y - mc1.y, mc1.y);
            mc1.z = fmaf(g4.z, xpv.z - mc1.z, mc1.z);
            mc1.w = fmaf(g4.w, xpv.w - mc1.w, mc1.w);
            mcur4[(size_t)(b * NSLOT + s1) * 64 + lane] = mc1;
            if (lane == 0) descL[s1] = (unsigned int)m1i;
          }
          e01 = __expf(l01 - c0);
          acc.x = fmaf(-e01, mo1.x, acc.x);
          acc.y = fmaf(-e01, mo1.y, acc.y);
          acc.z = fmaf(-e01, mo1.z, acc.z);
          acc.w = fmaf(-e01, mo1.w, acc.w);
          p1 = mc1.x * qv.x;
          p1 = fmaf(mc1.y, qv.y, p1);
          p1 = fmaf(mc1.z, qv.z, p1);
          p1 = fmaf(mc1.w, qv.w, p1);
        }
        // --- interleaved butterflies (2 independent chains)
#pragma unroll
        for (int off = 1; off < 64; off <<= 1) {
          p0 += __shfl_xor(p0, off, 64);
          p1 += __shfl_xor(p1, off, 64);
        }
        // --- finish: exp, accumulate, stats (only mc/p/e0/m live here)
        {
          const float cur = (p0 + qb) * 0.0625f;
          const float ce = __expf(cur - c0);
          acc.x = fmaf(ce, mc0.x, acc.x);
          acc.y = fmaf(ce, mc0.y, acc.y);
          acc.z = fmaf(ce, mc0.z, acc.z);
          acc.w = fmaf(ce, mc0.w, acc.w);
          if (lane == 0) {
            diffA[s0] = ce - e00;
            candV[s0] = cur;
            candI[s0] = m0i;
          }
        }
        if (v1) {
          const float cur = (p1 + qb) * 0.0625f;
          const float ce = __expf(cur - c0);
          acc.x = fmaf(ce, mc1.x, acc.x);
          acc.y = fmaf(ce, mc1.y, acc.y);
          acc.z = fmaf(ce, mc1.z, acc.z);
          acc.w = fmaf(ce, mc1.w, acc.w);
          if (lane == 0) {
            diffA[s1] = ce - e01;
            candV[s1] = cur;
            candI[s1] = m1i;
          }
        }
      }
      ((float4*)dpart[wvid])[lane] = acc;
    } else {
      // wave 15: candidate prep + per-step prefetches
#pragma unroll
      for (int jj = 0; jj < 4; ++jj) {
        const int j = lane + jj * 64;
        const int ii = topi[n * TOPC + j];
        const bool fresh = (tpos[ii] < 0);
        candV[NSLOT + j] = fresh ? topv[n * TOPC + j] : -INFINITY;
        candI[NSLOT + j] = fresh ? ii : 0x7FFFFFFF;
      }
      const float4 c0v = ctxp4[(size_t)(0 * N_ + n) * 64 + lane];
      const float4 c1v = ctxp4[(size_t)(1 * N_ + n) * 64 + lane];
      const float4 c2v = ctxp4[(size_t)(2 * N_ + n) * 64 + lane];
      const float4 c3v = ctxp4[(size_t)(3 * N_ + n) * 64 + lane];
      ((float4*)CTX0_s)[lane] = make_float4(c0v.x + c1v.x + c2v.x + c3v.x,
                                            c0v.y + c1v.y + c2v.y + c3v.y,
                                            c0v.z + c1v.z + c2v.z + c3v.z,
                                            c0v.w + c1v.w + c2v.w + c3v.w);
      ((float4*)xgp_s)[lane] = xgp4[(size_t)n * 64 + lane];
      if (t + 1 < S_) {
        ((float4*)qt_s[par ^ 1])[lane] = qt4[(size_t)(n + B_) * 64 + lane];
        ((float4*)xt_s[par ^ 1])[lane] = x4[(size_t)(b * S_ + t + 1) * 64 + lane];
      }
    }
    __syncthreads();  // B1

    // ===== PB: GEMV + denom (waves 0-14) || top-8 selection (wave 15)
    if (wvid < 15) {
      const int kbase = 17 * wvid;
      const int nr = (wvid == 14) ? 18 : 17;
      float mynum = 0.f;
      if (lane < nr) {
        const int k = (lane == 17) ? 255 : (kbase + lane);
        float nv = CTX0_s[k];
#pragma unroll
        for (int p = 0; p < 15; ++p) nv += dpart[p][k];
        mynum = nv;
      }
      float4 a1 = make_float4(0.f, 0.f, 0.f, 0.f);
      float4 a2 = make_float4(0.f, 0.f, 0.f, 0.f);
#pragma unroll
      for (int j = 0; j < 17; ++j) {
        const float nv = __int_as_float(__builtin_amdgcn_readlane(__float_as_int(mynum), j));
        a1.x = fmaf(nv, wreg[j].x, a1.x); a1.y = fmaf(nv, wreg[j].y, a1.y);
        a1.z = fmaf(nv, wreg[j].z, a1.z); a1.w = fmaf(nv, wreg[j].w, a1.w);
        const int r = kbase + j;
        const float4 w4 = (r >= CACHE0) ? wvlds4[(size_t)(r - CACHE0) * 64 + lane]
                                        : Wg4[(size_t)r * 64 + lane];
        a2.x = fmaf(nv, w4.x, a2.x); a2.y = fmaf(nv, w4.y, a2.y);
        a2.z = fmaf(nv, w4.z, a2.z); a2.w = fmaf(nv, w4.w, a2.w);
      }
      if (wvid == 14) {
        const float nv = __int_as_float(__builtin_amdgcn_readlane(__float_as_int(mynum), 17));
        a1.x = fmaf(nv, wreg[17].x, a1.x); a1.y = fmaf(nv, wreg[17].y, a1.y);
        a1.z = fmaf(nv, wreg[17].z, a1.z); a1.w = fmaf(nv, wreg[17].w, a1.w);
        const float4 w4 = wvlds4[(size_t)(255 - CACHE0) * 64 + lane];
        a2.x = fmaf(nv, w4.x, a2.x); a2.y = fmaf(nv, w4.y, a2.y);
        a2.z = fmaf(nv, w4.z, a2.z); a2.w = fmaf(nv, w4.w, a2.w);
      }
      ((float4*)fpart[wvid])[lane] = a1;
      ((float4*)fpart2[wvid])[lane] = a2;
      if (wvid == 0) {  // denominator (wave 0: GEMV is shorter than selection)
        double dsum = 0.0;
        for (int s2 = lane; s2 < Tc; s2 += 64) dsum += (double)diffA[s2];
#pragma unroll
        for (int off = 32; off > 0; off >>= 1) dsum += __shfl_down(dsum, off, 64);
        if (lane == 0) inv_esum = (float)(1.0 / (sum0s[t] + dsum));
      }
    } else if (t + 1 < S_) {
      // ---- wave 15: top-8 of 512 candidates via bitonic top-k merge.
      // key = sortable(float) << 11 | (2047 - idx): order == (v desc, idx asc)
      const float4 cv0 = ((const float4*)candV)[lane * 2];
      const float4 cv1 = ((const float4*)candV)[lane * 2 + 1];
      const int4 ci0 = ((const int4*)candI)[lane * 2];
      const int4 ci1 = ((const int4*)candI)[lane * 2 + 1];
      unsigned long long key[8];
      {
        const float vs[8] = {cv0.x, cv0.y, cv0.z, cv0.w, cv1.x, cv1.y, cv1.z, cv1.w};
        const int is[8] = {ci0.x, ci0.y, ci0.z, ci0.w, ci1.x, ci1.y, ci1.z, ci1.w};
#pragma unroll
        for (int j = 0; j < 8; ++j) {
          unsigned int bits = __float_as_uint(vs[j]);
          bits = (bits & 0x80000000u) ? ~bits : (bits | 0x80000000u);
          key[j] = ((unsigned long long)bits << 11) |
                   (unsigned long long)(2047 - (is[j] & 2047));
        }
      }
      // per-lane sort-8 desc (Batcher odd-even mergesort, 19 CE)
      CE8(0, 1) CE8(2, 3) CE8(4, 5) CE8(6, 7)
      CE8(0, 2) CE8(1, 3) CE8(4, 6) CE8(5, 7)
      CE8(1, 2) CE8(5, 6)
      CE8(0, 4) CE8(1, 5) CE8(2, 6) CE8(3, 7)
      CE8(2, 4) CE8(3, 5)
      CE8(1, 2) CE8(3, 4) CE8(5, 6)
      // 6-level butterfly: keep-top-8 merge (max(a[i], b[7-i]) is bitonic),
      // then 12-CE bitonic cleanup back to descending
#pragma unroll
      for (int off = 1; off < 64; off <<= 1) {
        unsigned long long pk[8];
#pragma unroll
        for (int j = 0; j < 8; ++j) pk[j] = shfl_xor_u64(key[7 - j], off);
#pragma unroll
        for (int j = 0; j < 8; ++j) key[j] = (pk[j] > key[j]) ? pk[j] : key[j];
        CE8(0, 4) CE8(1, 5) CE8(2, 6) CE8(3, 7)
        CE8(0, 2) CE8(1, 3) CE8(4, 6) CE8(5, 7)
        CE8(0, 1) CE8(2, 3) CE8(4, 5) CE8(6, 7)
      }
      // all lanes now hold the identical top-8 list; lane r takes rank r
      int myM = 2047 - (int)(key[0] & 2047);
#pragma unroll
      for (int r = 1; r < TK; ++r) {
        const int mr = 2047 - (int)(key[r] & 2047);
        if (lane == r) myM = mr;
      }
      int sOld = 0;
      bool fresh = false;
      if (lane < TK) {
        sOld = (int)tpos[myM];
        fresh = sOld < 0;
      }
      const unsigned long long fm = __ballot(fresh);
      if (lane < TK) {
        const int before = (int)__popcll(fm & ((1ull << lane) - 1ull));
        const int snew = fresh ? (Tc + before) : sOld;
        if (fresh) {
          tpos[myM] = (short)snew;
          candI[snew] = myM;
        }
        descL[snew] = (unsigned int)myM | ((fresh ? 1u : 0u) << 11) | (1u << 12);
      }
      if (lane == 0) Tcount = Tc + (int)__popcll(fm);
    }
    __syncthreads();  // B2

    // ===== PC: finalize out & gate =====
    if (tid < D_) {
      float o = 0.f;
#pragma unroll
      for (int p = 0; p < 15; ++p) o += fpart[p][tid];
      o = o * inv_esum + bv_s[tid];
      out[((size_t)b * S_ + t) * D_ + tid] = o;
    } else if (tid < 2 * D_) {
      const int d = tid - D_;
      float gg = 0.f;
#pragma unroll
      for (int p = 0; p < 15; ++p) gg += fpart2[p][d];
      const float gin = xgp_s[d] + gg * inv_esum + bvg_s[d];
      g_s[d] = 1.0f / (1.0f + __expf(-gin));
    }
    __syncthreads();  // B3
  }
}

// ---------------------------------------------------------------------------
extern "C" void kernel_launch(void* const* d_in, const int* in_sizes, int n_in,
                              void* d_out, int out_size, void* d_ws, size_t ws_size,
                              hipStream_t stream) {
  const float* x = (const float*)d_in[0];
  const float* mem0 = (const float*)d_in[1];
  const float* Wq = (const float*)d_in[2];
  const float* bq = (const float*)d_in[3];
  const float* Wk = (const float*)d_in[4];
  const float* bk = (const float*)d_in[5];
  const float* Wv = (const float*)d_in[6];
  const float* bv = (const float*)d_in[7];
  const float* Wg = (const float*)d_in[8];
  const float* bg = (const float*)d_in[9];
  float* out = (float*)d_out;
  float* ws = (float*)d_ws;

  size_t o = 0;
  float* WkT = ws + o;    o += (size_t)D_ * D_;
  float* qt = ws + o;     o += (size_t)N_ * D_;
  float* qbk = ws + o;    o += N_;
  float* xgp = ws + o;    o += (size_t)N_ * D_;
  float* L0 = ws + o;     o += (size_t)N_ * M_;
  float* M0 = ws + o;     o += N_;
  double* SumE0 = (double*)(ws + o); o += 2 * N_;
  float* ctxp = ws + o;   o += (size_t)KSPLIT * N_ * D_;
  float* topv = ws + o;   o += (size_t)N_ * TOPC;
  int* topi = (int*)(ws + o); o += (size_t)N_ * TOPC;
  float* WvWgB = ws + o;  o += (size_t)D_ * D_;
  float* bvg = ws + o;    o += D_;
  float* memcur = ws + o; o += (size_t)B_ * NSLOT * D_;

  k_wvwgT<<<dim3(81), dim3(256), 0, stream>>>(Wv, Wg, bv, bg, Wk, WvWgB, bvg, WkT);
  k_qproj<<<dim3(N_), dim3(256), 0, stream>>>(x, Wq, bq, bk, WkT, Wg, qt, qbk, xgp);
  k_L0<<<dim3(M_ / 64, N_ / 64), dim3(256), 0, stream>>>(qt, mem0, qbk, L0);
  k_sortstats<<<dim3(N_), dim3(1024), 0, stream>>>(L0, topv, topi, M0, SumE0);
  k_ctxpart<<<dim3(KSPLIT, N_ / 32, D_ / 64), dim3(256), 0, stream>>>(L0, M0, mem0, ctxp);
  k_scan<<<dim3(B_), dim3(1024), 0, stream>>>(x, mem0, Wv, bv, WvWgB, bvg, qt, qbk, xgp,
                                              L0, M0, SumE0, ctxp, topv, topi, memcur, out);
}